// Round 7
// baseline (77.606 us; speedup 1.0000x reference)
//
#include <hip/hip_runtime.h>

// MeanTopKPooling2D: x [16,112,112,128] f32 -> out [16,110,110,128] f32
// out[pos, c] = mean(top4 over q in [0,9) of x[b, pix(q, base)])
//   base = pos % 12100, b = pos/12100; with base = 9u+v:
//   w = v+4q; t = q*1344 + u + w/9; p = w%9
//   pix = t + 2*(t/110) + 112*(p/3) + (p%3)
//
// R7: R6's wave-uniform structure (one wave = two adjacent pos, float4/lane,
// SALU index chains) + INLINE-ASM load cluster: 9 volatile global_load_dwordx4
// with "=v" outputs force 36 value VGPRs live -> all 9 loads in flight per
// wave (R4-R6 showed the compiler's reg-pressure scheduler otherwise breaks
// the cluster to ~2-3 outstanding -> latency-bound at 51-75us).

#define NH 110
#define NW 110
#define NC 128
#define IH 112
#define IW 112
#define NPOS (NH * NW)            // 12100
#define TOTPOS (16 * NPOS)        // 193600
#define NWAVES (TOTPOS / 2)       // 96800
#define NWG (NWAVES / 4)          // 24200 blocks; 24200 % 8 == 0

typedef float f32x4 __attribute__((ext_vector_type(4)));

__global__ __launch_bounds__(256) void meantopk_kernel(const float* __restrict__ x,
                                                       float* __restrict__ out) {
    // XCD-aware chunked block swizzle (NWG % 8 == 0)
    unsigned bid = blockIdx.x;
    unsigned wg  = (bid & 7u) * (NWG / 8u) + (bid >> 3);

    unsigned lane = threadIdx.x & 63u;
    unsigned wid  = threadIdx.x >> 6;                     // wave in block, 0..3
    unsigned posA = __builtin_amdgcn_readfirstlane((wg * 4u + wid) * 2u);
    unsigned posB = posA + 1u;

    // scalar (SALU) decomposition for both positions
    unsigned baseA = posA % (unsigned)NPOS, bA = posA / (unsigned)NPOS;
    unsigned baseB = posB % (unsigned)NPOS, bB = posB / (unsigned)NPOS;
    unsigned uA = baseA / 9u, vsA = baseA % 9u;
    unsigned uB = baseB / 9u, vsB = baseB % 9u;
    unsigned imgA = bA * (IH * IW * NC * 4u);             // byte offset of image
    unsigned imgB = bB * (IH * IW * NC * 4u);

    const char* xb = reinterpret_cast<const char*>(x);
    unsigned laneq = (lane & 31u) * 16u;                  // byte offset within pixel
    bool hi = lane >= 32u;

    f32x4 va[9];
#pragma unroll
    for (int q = 0; q < 9; ++q) {
        unsigned wA = vsA + 4u * (unsigned)q;
        unsigned tA = (unsigned)q * 1344u + uA + wA / 9u;
        unsigned pA = wA % 9u;
        unsigned pixA = tA + 2u * (tA / 110u) + 112u * (pA / 3u) + (pA % 3u);
        unsigned offA = imgA + pixA * (NC * 4u);

        unsigned wB = vsB + 4u * (unsigned)q;
        unsigned tB = (unsigned)q * 1344u + uB + wB / 9u;
        unsigned pB = wB % 9u;
        unsigned pixB = tB + 2u * (tB / 110u) + 112u * (pB / 3u) + (pB % 3u);
        unsigned offB = imgB + pixB * (NC * 4u);

        unsigned off = offA + (hi ? (offB - offA) : 0u) + laneq;
        const char* addr = xb + off;
        // Volatile asm: stays clustered in issue order, dest quad stays live
        // until consumed -> 9 loads outstanding per wave.
        asm volatile("global_load_dwordx4 %0, %1, off"
                     : "=v"(va[q]) : "v"(addr) : "memory");
    }

    // Drain all 9 loads, then fence the scheduler so no consumer hoists above
    // the wait (hipcc hoists register-only ops past inline-asm waitcnt: rule 18).
    asm volatile("s_waitcnt vmcnt(0)" ::: "memory");
    __builtin_amdgcn_sched_barrier(0);

    float res[4];
#pragma unroll
    for (int e = 0; e < 4; ++e) {
        float a0 = va[0][e], a1 = va[1][e], a2 = va[2][e], a3 = va[3][e];
        float b0 = va[4][e], b1 = va[5][e], b2 = va[6][e], b3 = va[7][e];
        float v8 = va[8][e];
#define CSWP(p_, q_) { float hi_ = fmaxf(p_, q_); float lo_ = fminf(p_, q_); (p_) = hi_; (q_) = lo_; }
        // sort both quads descending (5 comparators each)
        CSWP(a0, a1); CSWP(a2, a3); CSWP(a0, a2); CSWP(a1, a3); CSWP(a1, a2);
        CSWP(b0, b1); CSWP(b2, b3); CSWP(b0, b2); CSWP(b1, b3); CSWP(b1, b2);
#undef CSWP
        // bitonic half-cleaner: top-4 multiset of the 8 (max side only)
        float m0 = fmaxf(a0, b3);
        float m1 = fmaxf(a1, b2);
        float m2 = fmaxf(a2, b1);
        float m3 = fmaxf(a3, b0);
        // top4 of {m0..m3, v8} = sum5 - min5
        float s  = m0 + m1 + m2 + m3 + v8;
        float mn = fminf(fminf(m0, m1), fminf(m2, m3));
        mn = fminf(mn, v8);
        res[e] = (s - mn) * 0.25f;
    }

    f32x4 r = {res[0], res[1], res[2], res[3]};
    // out bytes: posA*512 .. posA*512+1023 are exactly this wave's two pos
    f32x4* op = reinterpret_cast<f32x4*>(
        reinterpret_cast<char*>(out) + (size_t)posA * (NC * 4u) + lane * 16u);
    __builtin_nontemporal_store(r, op);
}

extern "C" void kernel_launch(void* const* d_in, const int* in_sizes, int n_in,
                              void* d_out, int out_size, void* d_ws, size_t ws_size,
                              hipStream_t stream) {
    const float* x = (const float*)d_in[0];
    float* out = (float*)d_out;
    meantopk_kernel<<<NWG, 256, 0, stream>>>(x, out);
}

// Round 8
// 51.497 us; speedup vs baseline: 1.5070x; 1.5070x over previous
//
#include <hip/hip_runtime.h>

// MeanTopKPooling2D: x [16,112,112,128] f32 -> out [16,110,110,128] f32
// out[pos, c] = mean(top4 over q in [0,9) of x[b, pix(q, base)])
//   P = q*12100 + base; p = P%9; t = P/9
//   pix = t + 2*(t/110) + 112*(p/3) + (p%3);  base = 9u+v -> t = q*1344+u+(v+4q)/9
//
// R8 = R4 (best, 51.1us) + __launch_bounds__(256, 4): min 4 waves/EU lifts the
// VGPR budget to 128 so the pre-RA scheduler stops compressing the 18-load
// cluster to ~4 outstanding (R4-R7 all showed reg-pressure-driven
// serialization; occupancy-targeting is the policy to change, not the
// schedule).

#define NH 110
#define NW 110
#define NC 128
#define IH 112
#define IW 112
#define NPOS (NH * NW)        // 12100
#define NWG 12100             // 16*12100*16 threads / 256

typedef float f32x4 __attribute__((ext_vector_type(4)));

__global__ __launch_bounds__(256, 4) void meantopk_kernel(const float* __restrict__ x,
                                                          float* __restrict__ out) {
    // --- bijective XCD-aware block swizzle (nwg = 12100, nwg%8 = 4) ---
    const unsigned NX = 8u;
    unsigned bid = blockIdx.x;
    const unsigned qq = NWG / NX;        // 1512
    const unsigned rr = NWG % NX;        // 4
    unsigned xcd = bid % NX;
    unsigned idx = bid / NX;
    unsigned wg = (xcd < rr ? xcd * (qq + 1u)
                            : rr * (qq + 1u) + (xcd - rr) * qq) + idx;

    unsigned tid = wg * 256u + threadIdx.x;
    unsigned c8  = tid & 15u;            // channel-group of 8
    unsigned pos = tid >> 4;             // b*12100 + base
    unsigned base = pos % (unsigned)NPOS;
    unsigned b    = pos / (unsigned)NPOS;
    unsigned u = base / 9u;
    unsigned v = base % 9u;

    const float* xb = x + (size_t)b * (IH * IW * NC) + c8 * 8u;

    float va[9][8];
#pragma unroll
    for (int q = 0; q < 9; ++q) {
        unsigned w = v + 4u * (unsigned)q;            // < 41
        unsigned t = (unsigned)q * 1344u + u + w / 9u;
        unsigned p = w % 9u;
        unsigned pix = t + 2u * (t / 110u) + 112u * (p / 3u) + (p % 3u);
        const f32x4* src = reinterpret_cast<const f32x4*>(xb + (size_t)pix * NC);
        f32x4 f0 = src[0];
        f32x4 f1 = src[1];
        va[q][0] = f0.x; va[q][1] = f0.y; va[q][2] = f0.z; va[q][3] = f0.w;
        va[q][4] = f1.x; va[q][5] = f1.y; va[q][6] = f1.z; va[q][7] = f1.w;
    }

    // Keep all loads issued before the merge network consumes anything.
    __builtin_amdgcn_sched_barrier(0);

    float res[8];
#pragma unroll
    for (int e = 0; e < 8; ++e) {
        float a0 = va[0][e], a1 = va[1][e], a2 = va[2][e], a3 = va[3][e];
        float b0 = va[4][e], b1 = va[5][e], b2 = va[6][e], b3 = va[7][e];
        float v8 = va[8][e];
#define CSWP(p_, q_) { float hi_ = fmaxf(p_, q_); float lo_ = fminf(p_, q_); (p_) = hi_; (q_) = lo_; }
        // sort both quads descending (5 comparators each)
        CSWP(a0, a1); CSWP(a2, a3); CSWP(a0, a2); CSWP(a1, a3); CSWP(a1, a2);
        CSWP(b0, b1); CSWP(b2, b3); CSWP(b0, b2); CSWP(b1, b3); CSWP(b1, b2);
#undef CSWP
        // bitonic half-cleaner: top-4 multiset of the 8 (max side only)
        float m0 = fmaxf(a0, b3);
        float m1 = fmaxf(a1, b2);
        float m2 = fmaxf(a2, b1);
        float m3 = fmaxf(a3, b0);
        // top4 of {m0..m3, v8} = sum5 - min5
        float s  = m0 + m1 + m2 + m3 + v8;
        float mn = fminf(fminf(m0, m1), fminf(m2, m3));
        mn = fminf(mn, v8);
        res[e] = (s - mn) * 0.25f;
    }

    f32x4 r0 = {res[0], res[1], res[2], res[3]};
    f32x4 r1 = {res[4], res[5], res[6], res[7]};
    f32x4* op = reinterpret_cast<f32x4*>(out + (size_t)pos * NC + c8 * 8u);
    __builtin_nontemporal_store(r0, op);
    __builtin_nontemporal_store(r1, op + 1);
}

extern "C" void kernel_launch(void* const* d_in, const int* in_sizes, int n_in,
                              void* d_out, int out_size, void* d_ws, size_t ws_size,
                              hipStream_t stream) {
    const float* x = (const float*)d_in[0];
    float* out = (float*)d_out;
    meantopk_kernel<<<NWG, 256, 0, stream>>>(x, out);
}